// Round 1
// baseline (55.231 us; speedup 1.0000x reference)
//
#include <hip/hip_runtime.h>
#include <math.h>

// Problem constants (from reference setup_inputs)
constexpr int B_ = 8, N_ = 32768, CAT_ = 128, FEAT_ = 128, K_ = 64;
constexpr float DELTA_ = 0.5f;

typedef __bf16 bf16x8 __attribute__((ext_vector_type(8)));
typedef float f32x4 __attribute__((ext_vector_type(4)));

constexpr int LDSTR = 136;                    // padded bf16 row stride (272 B, 16B-aligned)
constexpr int GEMM_BLOCKS = (B_ * N_) / 128;  // 2048 (128 n-rows per block)

__global__ __launch_bounds__(256, 4) void ocm_fused(
    const float* __restrict__ input,   // [B][N][CAT]
    const float* __restrict__ weight,  // [CAT][FEAT]
    const int* __restrict__ keys,      // [K]
    const float* __restrict__ values,  // [K][FEAT]
    float* __restrict__ out)           // [B][FEAT][N] ++ [CAT][FEAT]
{
    const int bid = blockIdx.x;
    const int tid = threadIdx.x;

    // ---------------- tail blocks: new_weight ----------------
    if (bid >= GEMM_BLOCKS) {
        float* outw = out + (size_t)B_ * FEAT_ * N_;
        const int r = bid - GEMM_BLOCKS;  // weight row 0..127
        // copy row r unless it is overwritten by a key update
        bool keyed = false;
        for (int i = 0; i < K_; ++i) keyed |= (keys[i] == r);
        if (!keyed && tid < FEAT_)
            outw[r * FEAT_ + tid] = weight[r * FEAT_ + tid];
        // blocks 0..K-1 additionally compute the norm row for keys[r]
        if (r < K_ && tid < 64) {
            const int key = keys[r];
            float a0 = DELTA_ * weight[key * FEAT_ + tid]      + (1.0f - DELTA_) * values[r * FEAT_ + tid];
            float a1 = DELTA_ * weight[key * FEAT_ + tid + 64] + (1.0f - DELTA_) * values[r * FEAT_ + tid + 64];
            float ss = a0 * a0 + a1 * a1;
            #pragma unroll
            for (int off = 32; off > 0; off >>= 1)
                ss += __shfl_down(ss, off, 64);
            float nrm = sqrtf(__shfl(ss, 0, 64));
            outw[key * FEAT_ + tid]      = nrm;
            outw[key * FEAT_ + tid + 64] = nrm;
        }
        return;
    }

    // ---------------- GEMM blocks ----------------
    __shared__ __bf16 wt[FEAT_ * LDSTR];  // wt[f][c] = weight[c][f], bf16, padded stride

    #pragma unroll
    for (int j = 0; j < (CAT_ * FEAT_) / 256; ++j) {
        int i = tid + j * 256;
        int c = i >> 7;            // weight row (CAT)
        int f = i & (FEAT_ - 1);   // weight col (FEAT)
        wt[f * LDSTR + c] = (__bf16)weight[i];
    }
    __syncthreads();

    const int wid  = tid >> 6;
    const int lane = tid & 63;
    const int qlo  = lane & 15;   // MFMA col / A row index
    const int qhi  = lane >> 4;   // 0..3, selects k-group of 8
    const int b    = bid >> 8;    // batch (256 n-blocks per batch)
    const int nb   = bid & 255;
    const int n0   = nb * 128 + wid * 32;  // this wave's n start (32 n per wave)

    f32x4 acc[8][2];
    #pragma unroll
    for (int i = 0; i < 8; ++i)
        #pragma unroll
        for (int j = 0; j < 2; ++j)
            acc[i][j] = (f32x4)0.0f;

    const float* in_base = input + ((size_t)b * N_ + n0) * CAT_;

    #pragma unroll
    for (int ck = 0; ck < 4; ++ck) {          // K-steps of 32
        bf16x8 bfrag[2];
        #pragma unroll
        for (int nt = 0; nt < 2; ++nt) {      // two 16-wide n subtiles
            const float* p = in_base + (size_t)(nt * 16 + qlo) * CAT_ + ck * 32 + qhi * 8;
            f32x4 v0 = *(const f32x4*)p;
            f32x4 v1 = *(const f32x4*)(p + 4);
            bf16x8 t;
            t[0] = (__bf16)v0[0]; t[1] = (__bf16)v0[1]; t[2] = (__bf16)v0[2]; t[3] = (__bf16)v0[3];
            t[4] = (__bf16)v1[0]; t[5] = (__bf16)v1[1]; t[6] = (__bf16)v1[2]; t[7] = (__bf16)v1[3];
            bfrag[nt] = t;
        }
        #pragma unroll
        for (int mt = 0; mt < 8; ++mt) {      // 8 f subtiles of 16
            bf16x8 afrag = *(const bf16x8*)&wt[(mt * 16 + qlo) * LDSTR + ck * 32 + qhi * 8];
            acc[mt][0] = __builtin_amdgcn_mfma_f32_16x16x32_bf16(afrag, bfrag[0], acc[mt][0], 0, 0, 0);
            acc[mt][1] = __builtin_amdgcn_mfma_f32_16x16x32_bf16(afrag, bfrag[1], acc[mt][1], 0, 0, 0);
        }
    }

    // epilogue: C/D layout col=lane&15, row=(lane>>4)*4+reg  (m89/m91 verified)
    float* outp = out + (size_t)b * FEAT_ * N_ + n0;
    #pragma unroll
    for (int mt = 0; mt < 8; ++mt) {
        #pragma unroll
        for (int nt = 0; nt < 2; ++nt) {
            #pragma unroll
            for (int r = 0; r < 4; ++r) {
                int f = mt * 16 + qhi * 4 + r;
                outp[(size_t)f * N_ + nt * 16 + qlo] = acc[mt][nt][r];
            }
        }
    }
}

extern "C" void kernel_launch(void* const* d_in, const int* in_sizes, int n_in,
                              void* d_out, int out_size, void* d_ws, size_t ws_size,
                              hipStream_t stream) {
    const float* input  = (const float*)d_in[0];
    const float* weight = (const float*)d_in[1];
    const int*   keys   = (const int*)d_in[2];
    const float* values = (const float*)d_in[3];
    float* out = (float*)d_out;
    ocm_fused<<<GEMM_BLOCKS + CAT_, 256, 0, stream>>>(input, weight, keys, values, out);
}